// Round 1
// baseline (999.134 us; speedup 1.0000x reference)
//
#include <hip/hip_runtime.h>

#define N_NODES 50000
#define N_EDGES 800000
#define NUM_GRAPHS 256
#define HID 128
#define IN_DIM 64
#define BN_EPS 1e-5f

// ---------------- CSR build ----------------
__global__ void k_count(const int* __restrict__ dst, int* __restrict__ cnt){
  int e = blockIdx.x*blockDim.x + threadIdx.x;
  if(e < N_EDGES) atomicAdd(&cnt[dst[e]], 1);
}

__global__ __launch_bounds__(1024) void k_scan(const int* __restrict__ cnt, int* __restrict__ rowptr,
                        int* __restrict__ fill, float* __restrict__ invdeg){
  __shared__ int part[1024];
  const int CH = (N_NODES + 1023)/1024; // 49
  int t = threadIdx.x;
  int start = t*CH, end = min(start+CH, N_NODES);
  int s = 0;
  for(int i=start;i<end;i++) s += cnt[i];
  part[t] = s; __syncthreads();
  for(int off=1; off<1024; off<<=1){
    int v = (t>=off)? part[t-off] : 0;
    __syncthreads();
    part[t] += v;
    __syncthreads();
  }
  int base = part[t] - s;   // exclusive prefix of this thread's chunk
  for(int i=start;i<end;i++){
    int c = cnt[i];
    rowptr[i] = base; fill[i] = base;
    invdeg[i] = 1.0f / (float)max(c,1);
    base += c;
  }
  if(t==1023) rowptr[N_NODES] = base;
}

__global__ void k_fill(const int* __restrict__ src, const int* __restrict__ dst,
                       int* __restrict__ fill, int* __restrict__ eidx){
  int e = blockIdx.x*blockDim.x + threadIdx.x;
  if(e < N_EDGES){
    int d = dst[e];
    int pos = atomicAdd(&fill[d], 1);
    eidx[pos] = src[e];
  }
}

// ---------------- mean aggregation (CSR gather) ----------------
template<int K>
__global__ void k_agg(const float* __restrict__ h, const int* __restrict__ eidx,
                      const int* __restrict__ rowptr, const float* __restrict__ invdeg,
                      float* __restrict__ agg){
  int n = blockIdx.x; int f = threadIdx.x;
  int b = rowptr[n], e = rowptr[n+1];
  float acc = 0.f;
  for(int i=b;i<e;i++){
    int s = eidx[i];                 // wave-uniform -> scalar load
    acc += h[(size_t)s*K + f];       // coalesced row read
  }
  agg[(size_t)n*K + f] = acc * invdeg[n];
}

// ---------------- raw = agg@Wn + h@Wr + b ----------------
template<int K>
__global__ __launch_bounds__(128) void k_linear(const float* __restrict__ hin, const float* __restrict__ agg,
                         const float* __restrict__ Wn, const float* __restrict__ Wr,
                         const float* __restrict__ bias, float* __restrict__ raw){
  const int R = 8;
  __shared__ float sA[R][K];
  __shared__ float sH[R][K];
  int r0 = blockIdx.x * R;
  int tid = threadIdx.x;
  for(int idx = tid; idx < R*K; idx += 128){
    int r = idx / K, k = idx % K;
    int row = r0 + r;
    float a=0.f, hh=0.f;
    if(row < N_NODES){ a = agg[(size_t)row*K+k]; hh = hin[(size_t)row*K+k]; }
    sA[r][k]=a; sH[r][k]=hh;
  }
  __syncthreads();
  int col = tid;
  float acc[R];
  #pragma unroll
  for(int r=0;r<R;r++) acc[r]=0.f;
  #pragma unroll 4
  for(int k=0;k<K;k++){
    float wn = Wn[k*HID + col];
    float wr = Wr[k*HID + col];
    #pragma unroll
    for(int r=0;r<R;r++) acc[r] += sA[r][k]*wn + sH[r][k]*wr;
  }
  float b = bias[col];
  #pragma unroll
  for(int r=0;r<R;r++){
    int row = r0+r;
    if(row < N_NODES) raw[(size_t)row*HID+col] = acc[r] + b;
  }
}

// ---------------- batchnorm ----------------
__global__ void k_colstats(const float* __restrict__ raw, float* __restrict__ colsum, float* __restrict__ colsq){
  int col = threadIdx.x;
  float s=0.f, s2=0.f;
  for(int row = blockIdx.x; row < N_NODES; row += gridDim.x){
    float v = raw[(size_t)row*HID + col];
    s += v; s2 += v*v;
  }
  atomicAdd(&colsum[col], s);
  atomicAdd(&colsq[col], s2);
}

__global__ void k_bnfinal(const float* __restrict__ colsum, const float* __restrict__ colsq,
                          const float* __restrict__ gamma, const float* __restrict__ beta,
                          float* __restrict__ scale, float* __restrict__ shift){
  int t = threadIdx.x;
  float mu  = colsum[t] * (1.0f/(float)N_NODES);
  float var = colsq[t]  * (1.0f/(float)N_NODES) - mu*mu;
  float rstd = rsqrtf(var + BN_EPS);
  float sc = rstd * gamma[t];
  scale[t] = sc;
  shift[t] = beta[t] - mu*sc;
}

__global__ void k_bnrelu(float* __restrict__ raw, const float* __restrict__ scale, const float* __restrict__ shift){
  size_t i = (size_t)blockIdx.x*blockDim.x + threadIdx.x;
  if(i < (size_t)N_NODES*HID){
    int col = (int)(i & (HID-1));
    float v = raw[i]*scale[col] + shift[col];
    raw[i] = fmaxf(v, 0.f);
  }
}

// ---------------- global mean pool (batch is sorted) ----------------
__global__ void k_pool(const float* __restrict__ h, const int* __restrict__ batch,
                       float* __restrict__ pooled, float* __restrict__ cnt){
  const int CH = 32;
  int f = threadIdx.x;
  int n0 = blockIdx.x * CH;
  int nEnd = min(n0+CH, N_NODES);
  float acc = 0.f; int cur = -1; int c = 0;
  for(int n=n0;n<nEnd;n++){
    int b = batch[n];
    if(b != cur){
      if(cur >= 0){
        atomicAdd(&pooled[cur*HID+f], acc);
        if(f==0) atomicAdd(&cnt[cur], (float)c);
      }
      acc = 0.f; c = 0; cur = b;
    }
    acc += h[(size_t)n*HID + f];
    c++;
  }
  if(cur >= 0){
    atomicAdd(&pooled[cur*HID+f], acc);
    if(f==0) atomicAdd(&cnt[cur], (float)c);
  }
}

// ---------------- MLP head: one wave per graph ----------------
__global__ void k_mlp(const float* __restrict__ pooled, const float* __restrict__ cnt,
                      const float* __restrict__ fc1W, const float* __restrict__ fc1b,
                      const float* __restrict__ fc2W, const float* __restrict__ fc2b,
                      float* __restrict__ out){
  __shared__ float p[HID];
  int g = blockIdx.x; int t = threadIdx.x;
  float ic = 1.0f / fmaxf(cnt[g], 1.0f);
  p[t]      = pooled[g*HID + t]      * ic;
  p[t + 64] = pooled[g*HID + t + 64] * ic;
  __syncthreads();
  float z = fc1b[t];
  #pragma unroll 4
  for(int k=0;k<HID;k++) z += p[k]*fc1W[k*64 + t];
  z = fmaxf(z, 0.f);
  float v = z * fc2W[t];
  #pragma unroll
  for(int off=32; off>0; off>>=1) v += __shfl_down(v, off, 64);
  if(t==0) out[g] = 1.0f/(1.0f + expf(-(v + fc2b[0])));
}

extern "C" void kernel_launch(void* const* d_in, const int* in_sizes, int n_in,
                              void* d_out, int out_size, void* d_ws, size_t ws_size,
                              hipStream_t stream){
  const float* x    = (const float*)d_in[0];
  const int*   ei   = (const int*)d_in[1];
  const int*   batch= (const int*)d_in[2];
  const float* Wn0=(const float*)d_in[3]; const float* Wr0=(const float*)d_in[4]; const float* b0=(const float*)d_in[5];
  const float* Wn1=(const float*)d_in[6]; const float* Wr1=(const float*)d_in[7]; const float* b1=(const float*)d_in[8];
  const float* Wn2=(const float*)d_in[9]; const float* Wr2=(const float*)d_in[10]; const float* b2=(const float*)d_in[11];
  const float* gamma=(const float*)d_in[12]; const float* beta=(const float*)d_in[13];
  const float* fc1W=(const float*)d_in[14]; const float* fc1b=(const float*)d_in[15];
  const float* fc2W=(const float*)d_in[16]; const float* fc2b=(const float*)d_in[17];
  float* out = (float*)d_out;

  char* ws = (char*)d_ws;
  size_t off = 0;
  auto alloc = [&](size_t bytes)->char*{ char* p = ws + off; off += (bytes + 255) & ~(size_t)255; return p; };
  const size_t NF = (size_t)N_NODES * HID;
  float* A      = (float*)alloc(NF*4);
  float* B      = (float*)alloc(NF*4);
  float* AGG    = (float*)alloc(NF*4);
  float* invdeg = (float*)alloc((size_t)N_NODES*4);
  float* colsum = (float*)alloc(2*HID*4);      // colsum | colsq (one memset)
  float* colsq  = colsum + HID;
  float* scale  = (float*)alloc(2*HID*4);      // scale | shift
  float* shift  = scale + HID;
  float* pooled = (float*)alloc(((size_t)NUM_GRAPHS*HID + NUM_GRAPHS)*4); // pooled | cnt
  float* cnt    = pooled + (size_t)NUM_GRAPHS*HID;
  int* degcnt = (int*)alloc((size_t)N_NODES*4);
  int* rowptr = (int*)alloc((size_t)(N_NODES+1)*4);
  int* fill   = (int*)alloc((size_t)N_NODES*4);
  int* eidx   = (int*)alloc((size_t)N_EDGES*4);

  const int* src = ei;
  const int* dst = ei + N_EDGES;

  // CSR build
  hipMemsetAsync(degcnt, 0, (size_t)N_NODES*4, stream);
  k_count<<<(N_EDGES+255)/256, 256, 0, stream>>>(dst, degcnt);
  k_scan<<<1, 1024, 0, stream>>>(degcnt, rowptr, fill, invdeg);
  k_fill<<<(N_EDGES+255)/256, 256, 0, stream>>>(src, dst, fill, eidx);

  // ---- layer 0 (in=64) ----
  k_agg<IN_DIM><<<N_NODES, IN_DIM, 0, stream>>>(x, eidx, rowptr, invdeg, AGG);
  k_linear<IN_DIM><<<(N_NODES+7)/8, 128, 0, stream>>>(x, AGG, Wn0, Wr0, b0, A);
  hipMemsetAsync(colsum, 0, 2*HID*4, stream);
  k_colstats<<<256, 128, 0, stream>>>(A, colsum, colsq);
  k_bnfinal<<<1, 128, 0, stream>>>(colsum, colsq, gamma+0*HID, beta+0*HID, scale, shift);
  k_bnrelu<<<(int)((NF+255)/256), 256, 0, stream>>>(A, scale, shift);

  // ---- layer 1 ----
  k_agg<HID><<<N_NODES, HID, 0, stream>>>(A, eidx, rowptr, invdeg, AGG);
  k_linear<HID><<<(N_NODES+7)/8, 128, 0, stream>>>(A, AGG, Wn1, Wr1, b1, B);
  hipMemsetAsync(colsum, 0, 2*HID*4, stream);
  k_colstats<<<256, 128, 0, stream>>>(B, colsum, colsq);
  k_bnfinal<<<1, 128, 0, stream>>>(colsum, colsq, gamma+1*HID, beta+1*HID, scale, shift);
  k_bnrelu<<<(int)((NF+255)/256), 256, 0, stream>>>(B, scale, shift);

  // ---- layer 2 ----
  k_agg<HID><<<N_NODES, HID, 0, stream>>>(B, eidx, rowptr, invdeg, AGG);
  k_linear<HID><<<(N_NODES+7)/8, 128, 0, stream>>>(B, AGG, Wn2, Wr2, b2, A);
  hipMemsetAsync(colsum, 0, 2*HID*4, stream);
  k_colstats<<<256, 128, 0, stream>>>(A, colsum, colsq);
  k_bnfinal<<<1, 128, 0, stream>>>(colsum, colsq, gamma+2*HID, beta+2*HID, scale, shift);
  k_bnrelu<<<(int)((NF+255)/256), 256, 0, stream>>>(A, scale, shift);

  // ---- pool + MLP head ----
  hipMemsetAsync(pooled, 0, ((size_t)NUM_GRAPHS*HID + NUM_GRAPHS)*4, stream);
  k_pool<<<(N_NODES+31)/32, 128, 0, stream>>>(A, batch, pooled, cnt);
  k_mlp<<<NUM_GRAPHS, 64, 0, stream>>>(pooled, cnt, fc1W, fc1b, fc2W, fc2b, out);
}

// Round 2
// 595.694 us; speedup vs baseline: 1.6773x; 1.6773x over previous
//
#include <hip/hip_runtime.h>

#define N_NODES 50000
#define N_EDGES 800000
#define NUM_GRAPHS 256
#define HID 128
#define IN_DIM 64
#define BN_EPS 1e-5f
#define SPREAD 64           // spread copies for column-stat atomics
#define SB 98               // scan blocks: 98*512 = 50176 >= 50000

// ---------------- CSR build ----------------
__global__ void k_count(const int* __restrict__ dst, int* __restrict__ cnt){
  int e = blockIdx.x*blockDim.x + threadIdx.x;
  if(e < N_EDGES) atomicAdd(&cnt[dst[e]], 1);
}

// phase A: per-block sums of 512 counts
__global__ __launch_bounds__(256) void k_scanA(const int* __restrict__ cnt, int* __restrict__ blocksum){
  __shared__ int sh[256];
  int t = threadIdx.x;
  int i0 = blockIdx.x*512 + 2*t;
  int s = 0;
  if(i0   < N_NODES) s += cnt[i0];
  if(i0+1 < N_NODES) s += cnt[i0+1];
  sh[t] = s; __syncthreads();
  for(int off=128; off>0; off>>=1){
    if(t < off) sh[t] += sh[t+off];
    __syncthreads();
  }
  if(t==0) blocksum[blockIdx.x] = sh[0];
}

// phase B: exclusive scan of SB block sums (single block)
__global__ __launch_bounds__(128) void k_scanB(const int* __restrict__ blocksum, int* __restrict__ blockpre,
                                               int* __restrict__ rowptr){
  __shared__ int sh[128];
  int t = threadIdx.x;
  int v = (t < SB) ? blocksum[t] : 0;
  sh[t] = v; __syncthreads();
  for(int off=1; off<128; off<<=1){
    int u = (t>=off) ? sh[t-off] : 0;
    __syncthreads();
    sh[t] += u;
    __syncthreads();
  }
  if(t < SB) blockpre[t] = sh[t] - v;   // exclusive
  if(t==0) rowptr[N_NODES] = N_EDGES;   // total is always N_EDGES
}

// phase C: write rowptr / fill / invdeg
__global__ __launch_bounds__(256) void k_scanC(const int* __restrict__ cnt, const int* __restrict__ blockpre,
                                               int* __restrict__ rowptr, int* __restrict__ fill,
                                               float* __restrict__ invdeg){
  __shared__ int sh[256];
  int t = threadIdx.x;
  int i0 = blockIdx.x*512 + 2*t;
  int c0 = (i0   < N_NODES) ? cnt[i0]   : 0;
  int c1 = (i0+1 < N_NODES) ? cnt[i0+1] : 0;
  int loc = c0 + c1;
  sh[t] = loc; __syncthreads();
  for(int off=1; off<256; off<<=1){
    int u = (t>=off) ? sh[t-off] : 0;
    __syncthreads();
    sh[t] += u;
    __syncthreads();
  }
  int base = blockpre[blockIdx.x] + sh[t] - loc;  // global exclusive prefix
  if(i0 < N_NODES){
    rowptr[i0] = base; fill[i0] = base;
    invdeg[i0] = 1.0f / (float)max(c0,1);
  }
  if(i0+1 < N_NODES){
    rowptr[i0+1] = base + c0; fill[i0+1] = base + c0;
    invdeg[i0+1] = 1.0f / (float)max(c1,1);
  }
}

__global__ void k_fill(const int* __restrict__ src, const int* __restrict__ dst,
                       int* __restrict__ fill, int* __restrict__ eidx){
  int e = blockIdx.x*blockDim.x + threadIdx.x;
  if(e < N_EDGES){
    int d = dst[e];
    int pos = atomicAdd(&fill[d], 1);
    eidx[pos] = src[e];
  }
}

// ---------------- mean aggregation (one wave per node, float4) ----------------
// If APPLY: each loaded neighbor row v is transformed relu(v*scale+shift) first
// (h buffer stays PRE-BN in memory; BN+ReLU applied on the fly).
template<int K, bool APPLY>
__global__ __launch_bounds__(256) void k_agg(const float* __restrict__ h, const int* __restrict__ eidx,
                      const int* __restrict__ rowptr, const float* __restrict__ invdeg,
                      const float* __restrict__ scale, const float* __restrict__ shift,
                      float* __restrict__ agg){
  const int F4  = K/4;     // float4 lanes per row (32 for K=128, 16 for K=64)
  const int RPI = 64/F4;   // rows per wave-iteration (2 or 4)
  int wave = threadIdx.x >> 6;
  int lane = threadIdx.x & 63;
  int n = blockIdx.x*4 + wave;           // grid*4 == N_NODES exactly
  int b = rowptr[n], e = rowptr[n+1];
  int r = lane / F4, q = lane % F4;
  float4 sc, sf;
  if(APPLY){ sc = ((const float4*)scale)[q]; sf = ((const float4*)shift)[q]; }
  float4 acc = {0.f,0.f,0.f,0.f};
  for(int i = b + r; i < e; i += RPI){
    int s = eidx[i];
    float4 v = ((const float4*)h)[(size_t)s*F4 + q];
    if(APPLY){
      v.x = fmaxf(fmaf(v.x, sc.x, sf.x), 0.f);
      v.y = fmaxf(fmaf(v.y, sc.y, sf.y), 0.f);
      v.z = fmaxf(fmaf(v.z, sc.z, sf.z), 0.f);
      v.w = fmaxf(fmaf(v.w, sc.w, sf.w), 0.f);
    }
    acc.x += v.x; acc.y += v.y; acc.z += v.z; acc.w += v.w;
  }
  for(int off = F4; off < 64; off <<= 1){
    acc.x += __shfl_xor(acc.x, off, 64);
    acc.y += __shfl_xor(acc.y, off, 64);
    acc.z += __shfl_xor(acc.z, off, 64);
    acc.w += __shfl_xor(acc.w, off, 64);
  }
  if(lane < F4){
    float id = invdeg[n];
    float4 o = {acc.x*id, acc.y*id, acc.z*id, acc.w*id};
    ((float4*)agg)[(size_t)n*F4 + q] = o;
  }
}

// ---------------- raw = agg@Wn + relu(bn(hin))@Wr + b, with col-stats epilogue ----------------
template<int K, bool APPLY>
__global__ __launch_bounds__(128) void k_linear(const float* __restrict__ hin, const float* __restrict__ agg,
                         const float* __restrict__ scale, const float* __restrict__ shift,
                         const float* __restrict__ Wn, const float* __restrict__ Wr,
                         const float* __restrict__ bias, float* __restrict__ raw,
                         float* __restrict__ psum, float* __restrict__ psq){
  const int R = 16;                 // 50000/16 = 3125 blocks exactly
  const int F4 = K/4;
  __shared__ float4 sA[R][F4];
  __shared__ float4 sH[R][F4];
  int tid = threadIdx.x;
  int r0 = blockIdx.x * R;
  for(int idx = tid; idx < R*F4; idx += 128){
    int r = idx / F4, q = idx % F4;
    size_t ro = (size_t)(r0 + r)*F4 + q;
    float4 a  = ((const float4*)agg)[ro];
    float4 h4 = ((const float4*)hin)[ro];
    if(APPLY){
      float4 sc = ((const float4*)scale)[q], sf = ((const float4*)shift)[q];
      h4.x = fmaxf(fmaf(h4.x, sc.x, sf.x), 0.f);
      h4.y = fmaxf(fmaf(h4.y, sc.y, sf.y), 0.f);
      h4.z = fmaxf(fmaf(h4.z, sc.z, sf.z), 0.f);
      h4.w = fmaxf(fmaf(h4.w, sc.w, sf.w), 0.f);
    }
    sA[r][q] = a; sH[r][q] = h4;
  }
  __syncthreads();
  int col = tid;
  float acc[R];
  #pragma unroll
  for(int r=0;r<R;r++) acc[r] = 0.f;
  for(int k4=0; k4<F4; k4++){
    int kb = 4*k4;
    float wn0 = Wn[(kb+0)*HID+col], wn1 = Wn[(kb+1)*HID+col];
    float wn2 = Wn[(kb+2)*HID+col], wn3 = Wn[(kb+3)*HID+col];
    float wr0 = Wr[(kb+0)*HID+col], wr1 = Wr[(kb+1)*HID+col];
    float wr2 = Wr[(kb+2)*HID+col], wr3 = Wr[(kb+3)*HID+col];
    #pragma unroll
    for(int r=0;r<R;r++){
      float4 a = sA[r][k4], h = sH[r][k4];
      acc[r] += a.x*wn0 + a.y*wn1 + a.z*wn2 + a.w*wn3
              + h.x*wr0 + h.y*wr1 + h.z*wr2 + h.w*wr3;
    }
  }
  float b = bias[col];
  float s = 0.f, s2 = 0.f;
  #pragma unroll
  for(int r=0;r<R;r++){
    float v = acc[r] + b;
    raw[(size_t)(r0+r)*HID + col] = v;
    s += v; s2 += v*v;
  }
  int sp = blockIdx.x & (SPREAD-1);
  atomicAdd(&psum[sp*HID + col], s);
  atomicAdd(&psq [sp*HID + col], s2);
}

// ---------------- reduce spread col-stats -> scale/shift ----------------
__global__ void k_bnfinal(const float* __restrict__ psum, const float* __restrict__ psq,
                          const float* __restrict__ gamma, const float* __restrict__ beta,
                          float* __restrict__ scale, float* __restrict__ shift){
  int t = threadIdx.x;
  float s = 0.f, s2 = 0.f;
  for(int i=0;i<SPREAD;i++){ s += psum[i*HID+t]; s2 += psq[i*HID+t]; }
  float mu  = s  * (1.0f/(float)N_NODES);
  float var = s2 * (1.0f/(float)N_NODES) - mu*mu;
  float rstd = rsqrtf(var + BN_EPS);
  float sc = rstd * gamma[t];
  scale[t] = sc;
  shift[t] = beta[t] - mu*sc;
}

// ---------------- global mean pool (batch sorted; applies layer-2 BN+ReLU) ----------------
__global__ void k_pool(const float* __restrict__ h, const int* __restrict__ batch,
                       const float* __restrict__ scale, const float* __restrict__ shift,
                       float* __restrict__ pooled, float* __restrict__ cnt){
  const int CH = 32;
  int f = threadIdx.x;
  float sc = scale[f], sf = shift[f];
  int n0 = blockIdx.x * CH;
  int nEnd = min(n0+CH, N_NODES);
  float acc = 0.f; int cur = -1; int c = 0;
  for(int n=n0;n<nEnd;n++){
    int b = batch[n];
    if(b != cur){
      if(cur >= 0){
        atomicAdd(&pooled[cur*HID+f], acc);
        if(f==0) atomicAdd(&cnt[cur], (float)c);
      }
      acc = 0.f; c = 0; cur = b;
    }
    float v = h[(size_t)n*HID + f];
    acc += fmaxf(fmaf(v, sc, sf), 0.f);
    c++;
  }
  if(cur >= 0){
    atomicAdd(&pooled[cur*HID+f], acc);
    if(f==0) atomicAdd(&cnt[cur], (float)c);
  }
}

// ---------------- MLP head: one wave per graph ----------------
__global__ void k_mlp(const float* __restrict__ pooled, const float* __restrict__ cnt,
                      const float* __restrict__ fc1W, const float* __restrict__ fc1b,
                      const float* __restrict__ fc2W, const float* __restrict__ fc2b,
                      float* __restrict__ out){
  __shared__ float p[HID];
  int g = blockIdx.x; int t = threadIdx.x;
  float ic = 1.0f / fmaxf(cnt[g], 1.0f);
  p[t]      = pooled[g*HID + t]      * ic;
  p[t + 64] = pooled[g*HID + t + 64] * ic;
  __syncthreads();
  float z = fc1b[t];
  #pragma unroll 4
  for(int k=0;k<HID;k++) z += p[k]*fc1W[k*64 + t];
  z = fmaxf(z, 0.f);
  float v = z * fc2W[t];
  #pragma unroll
  for(int off=32; off>0; off>>=1) v += __shfl_down(v, off, 64);
  if(t==0) out[g] = 1.0f/(1.0f + expf(-(v + fc2b[0])));
}

extern "C" void kernel_launch(void* const* d_in, const int* in_sizes, int n_in,
                              void* d_out, int out_size, void* d_ws, size_t ws_size,
                              hipStream_t stream){
  const float* x    = (const float*)d_in[0];
  const int*   ei   = (const int*)d_in[1];
  const int*   batch= (const int*)d_in[2];
  const float* Wn0=(const float*)d_in[3]; const float* Wr0=(const float*)d_in[4]; const float* b0=(const float*)d_in[5];
  const float* Wn1=(const float*)d_in[6]; const float* Wr1=(const float*)d_in[7]; const float* b1=(const float*)d_in[8];
  const float* Wn2=(const float*)d_in[9]; const float* Wr2=(const float*)d_in[10]; const float* b2=(const float*)d_in[11];
  const float* gamma=(const float*)d_in[12]; const float* beta=(const float*)d_in[13];
  const float* fc1W=(const float*)d_in[14]; const float* fc1b=(const float*)d_in[15];
  const float* fc2W=(const float*)d_in[16]; const float* fc2b=(const float*)d_in[17];
  float* out = (float*)d_out;

  char* ws = (char*)d_ws;
  size_t off = 0;
  auto alloc = [&](size_t bytes)->char*{ char* p = ws + off; off += (bytes + 255) & ~(size_t)255; return p; };
  const size_t NF = (size_t)N_NODES * HID;

  // --- zeroed region (single memset): degcnt | psum/psq[3 layers] | pooled+cnt ---
  char* zero0   = ws + off;
  int*   degcnt = (int*)alloc((size_t)N_NODES*4);
  float* pstats = (float*)alloc((size_t)3*2*SPREAD*HID*4);  // [layer][sum|sq][SPREAD][HID]
  float* pooled = (float*)alloc(((size_t)NUM_GRAPHS*HID + NUM_GRAPHS)*4);
  float* cnt    = pooled + (size_t)NUM_GRAPHS*HID;
  size_t zbytes = (size_t)((ws + off) - zero0);

  // --- non-zeroed scratch ---
  float* A      = (float*)alloc(NF*4);
  float* B      = (float*)alloc(NF*4);
  float* AGG    = (float*)alloc(NF*4);
  float* invdeg = (float*)alloc((size_t)N_NODES*4);
  int* rowptr   = (int*)alloc((size_t)(N_NODES+1)*4);
  int* fill     = (int*)alloc((size_t)N_NODES*4);
  int* eidx     = (int*)alloc((size_t)N_EDGES*4);
  int* blocksum = (int*)alloc((size_t)SB*4);
  int* blockpre = (int*)alloc((size_t)SB*4);
  float* ss     = (float*)alloc((size_t)3*2*HID*4);  // [layer][scale|shift][HID]

  auto psumL = [&](int l){ return pstats + (size_t)l*2*SPREAD*HID; };
  auto psqL  = [&](int l){ return pstats + (size_t)l*2*SPREAD*HID + (size_t)SPREAD*HID; };
  auto scaleL= [&](int l){ return ss + (size_t)l*2*HID; };
  auto shiftL= [&](int l){ return ss + (size_t)l*2*HID + HID; };

  const int* src = ei;
  const int* dst = ei + N_EDGES;

  hipMemsetAsync(zero0, 0, zbytes, stream);

  // CSR build
  k_count<<<(N_EDGES+255)/256, 256, 0, stream>>>(dst, degcnt);
  k_scanA<<<SB, 256, 0, stream>>>(degcnt, blocksum);
  k_scanB<<<1, 128, 0, stream>>>(blocksum, blockpre, rowptr);
  k_scanC<<<SB, 256, 0, stream>>>(degcnt, blockpre, rowptr, fill, invdeg);
  k_fill<<<(N_EDGES+255)/256, 256, 0, stream>>>(src, dst, fill, eidx);

  // ---- layer 0 (in=64, no BN on input x) ----
  k_agg<IN_DIM,false><<<N_NODES/4, 256, 0, stream>>>(x, eidx, rowptr, invdeg, nullptr, nullptr, AGG);
  k_linear<IN_DIM,false><<<N_NODES/16, 128, 0, stream>>>(x, AGG, nullptr, nullptr, Wn0, Wr0, b0, A, psumL(0), psqL(0));
  k_bnfinal<<<1, 128, 0, stream>>>(psumL(0), psqL(0), gamma+0*HID, beta+0*HID, scaleL(0), shiftL(0));

  // ---- layer 1 (A holds pre-BN raw; BN0 applied on the fly) ----
  k_agg<HID,true><<<N_NODES/4, 256, 0, stream>>>(A, eidx, rowptr, invdeg, scaleL(0), shiftL(0), AGG);
  k_linear<HID,true><<<N_NODES/16, 128, 0, stream>>>(A, AGG, scaleL(0), shiftL(0), Wn1, Wr1, b1, B, psumL(1), psqL(1));
  k_bnfinal<<<1, 128, 0, stream>>>(psumL(1), psqL(1), gamma+1*HID, beta+1*HID, scaleL(1), shiftL(1));

  // ---- layer 2 ----
  k_agg<HID,true><<<N_NODES/4, 256, 0, stream>>>(B, eidx, rowptr, invdeg, scaleL(1), shiftL(1), AGG);
  k_linear<HID,true><<<N_NODES/16, 128, 0, stream>>>(B, AGG, scaleL(1), shiftL(1), Wn2, Wr2, b2, A, psumL(2), psqL(2));
  k_bnfinal<<<1, 128, 0, stream>>>(psumL(2), psqL(2), gamma+2*HID, beta+2*HID, scaleL(2), shiftL(2));

  // ---- pool (applies BN2+ReLU) + MLP head ----
  k_pool<<<(N_NODES+31)/32, 128, 0, stream>>>(A, batch, scaleL(2), shiftL(2), pooled, cnt);
  k_mlp<<<NUM_GRAPHS, 64, 0, stream>>>(pooled, cnt, fc1W, fc1b, fc2W, fc2b, out);
}

// Round 3
// 386.826 us; speedup vs baseline: 2.5829x; 1.5400x over previous
//
#include <hip/hip_runtime.h>

#define N_NODES 50000
#define N_EDGES 800000
#define NUM_GRAPHS 256
#define HID 128
#define IN_DIM 64
#define BN_EPS 1e-5f
#define SPREAD 64
#define SB 98               // scan blocks: 98*512 = 50176 >= 50000

typedef __attribute__((ext_vector_type(8))) short bf16x8;
typedef __attribute__((ext_vector_type(4))) float f32x4;

// ---- bf16 helpers (storage = ushort) ----
__device__ __forceinline__ float bf2f(unsigned short u){ union{unsigned i;float f;}c; c.i=((unsigned)u)<<16; return c.f; }
__device__ __forceinline__ float bflo(unsigned w){ union{unsigned i;float f;}c; c.i=w<<16; return c.f; }
__device__ __forceinline__ float bfhi(unsigned w){ union{unsigned i;float f;}c; c.i=w&0xFFFF0000u; return c.f; }
__device__ __forceinline__ unsigned short f2bf(float f){ union{float f;unsigned i;}c; c.f=f; unsigned r=c.i+0x7FFF+((c.i>>16)&1); return (unsigned short)(r>>16); }
__device__ __forceinline__ unsigned fpack(float a, float b){ // a->low16, b->high16 (RNE)
  union{float f;unsigned i;}ca,cb; ca.f=a; cb.f=b;
  unsigned ra=((ca.i+0x7FFF+((ca.i>>16)&1))>>16)&0xFFFFu;
  unsigned rb=(cb.i+0x7FFF+((cb.i>>16)&1))&0xFFFF0000u;
  return ra|rb;
}

// ---------------- CSR build ----------------
__global__ void k_count(const int* __restrict__ dst, int* __restrict__ cnt){
  int e = blockIdx.x*blockDim.x + threadIdx.x;
  if(e < N_EDGES) atomicAdd(&cnt[dst[e]], 1);
}

__global__ __launch_bounds__(256) void k_scanA(const int* __restrict__ cnt, int* __restrict__ blocksum){
  __shared__ int sh[256];
  int t = threadIdx.x;
  int i0 = blockIdx.x*512 + 2*t;
  int s = 0;
  if(i0   < N_NODES) s += cnt[i0];
  if(i0+1 < N_NODES) s += cnt[i0+1];
  sh[t] = s; __syncthreads();
  for(int off=128; off>0; off>>=1){
    if(t < off) sh[t] += sh[t+off];
    __syncthreads();
  }
  if(t==0) blocksum[blockIdx.x] = sh[0];
}

__global__ __launch_bounds__(128) void k_scanB(const int* __restrict__ blocksum, int* __restrict__ blockpre,
                                               int* __restrict__ rowptr){
  __shared__ int sh[128];
  int t = threadIdx.x;
  int v = (t < SB) ? blocksum[t] : 0;
  sh[t] = v; __syncthreads();
  for(int off=1; off<128; off<<=1){
    int u = (t>=off) ? sh[t-off] : 0;
    __syncthreads();
    sh[t] += u;
    __syncthreads();
  }
  if(t < SB) blockpre[t] = sh[t] - v;
  if(t==0) rowptr[N_NODES] = N_EDGES;
}

__global__ __launch_bounds__(256) void k_scanC(const int* __restrict__ cnt, const int* __restrict__ blockpre,
                                               int* __restrict__ rowptr, int* __restrict__ fill,
                                               float* __restrict__ invdeg){
  __shared__ int sh[256];
  int t = threadIdx.x;
  int i0 = blockIdx.x*512 + 2*t;
  int c0 = (i0   < N_NODES) ? cnt[i0]   : 0;
  int c1 = (i0+1 < N_NODES) ? cnt[i0+1] : 0;
  int loc = c0 + c1;
  sh[t] = loc; __syncthreads();
  for(int off=1; off<256; off<<=1){
    int u = (t>=off) ? sh[t-off] : 0;
    __syncthreads();
    sh[t] += u;
    __syncthreads();
  }
  int base = blockpre[blockIdx.x] + sh[t] - loc;
  if(i0 < N_NODES){
    rowptr[i0] = base; fill[i0] = base;
    invdeg[i0] = 1.0f / (float)max(c0,1);
  }
  if(i0+1 < N_NODES){
    rowptr[i0+1] = base + c0; fill[i0+1] = base + c0;
    invdeg[i0+1] = 1.0f / (float)max(c1,1);
  }
}

__global__ void k_fill(const int* __restrict__ src, const int* __restrict__ dst,
                       int* __restrict__ fill, int* __restrict__ eidx){
  int e = blockIdx.x*blockDim.x + threadIdx.x;
  if(e < N_EDGES){
    int d = dst[e];
    int pos = atomicAdd(&fill[d], 1);
    eidx[pos] = src[e];
  }
}

// ---------------- pack x (fp32) -> F0 H-part (bf16) ----------------
__global__ __launch_bounds__(256) void k_packX(const float* __restrict__ x, unsigned short* __restrict__ F0){
  int tid = blockIdx.x*256 + threadIdx.x;   // 50000*8
  if(tid >= N_NODES*8) return;
  int row = tid>>3, q = tid&7;
  float4 a = ((const float4*)x)[(size_t)row*16 + q*2];
  float4 b = ((const float4*)x)[(size_t)row*16 + q*2 + 1];
  uint4 o;
  o.x = fpack(a.x, a.y); o.y = fpack(a.z, a.w);
  o.z = fpack(b.x, b.y); o.w = fpack(b.z, b.w);
  ((uint4*)F0)[(size_t)row*16 + 8 + q] = o;   // F0 row stride 128 bf16 = 16 uint4; H at col 64
}

// ---------------- pack weights into MFMA B-frag order ----------------
// Bp[(nt*NKS+ks)*64+lane] = 8 bf16: Wcat[ks*32+quad*8+j][nt*16+m], Wcat=[Wn;Wr]
template<int KH>
__global__ __launch_bounds__(256) void k_packW(const float* __restrict__ Wn, const float* __restrict__ Wr,
                                               unsigned short* __restrict__ Bp){
  const int NKS = (2*KH)/32;
  int id = blockIdx.x*256 + threadIdx.x;
  if(id >= 8*NKS*64) return;
  int lane = id & 63;
  int ks = (id>>6) % NKS;
  int nt = (id>>6) / NKS;
  int quad = lane>>4, m = lane&15;
  int c = nt*16 + m;
  unsigned short v[8];
  #pragma unroll
  for(int j=0;j<8;j++){
    int k = ks*32 + quad*8 + j;
    float w = (k < KH) ? Wn[(size_t)k*HID + c] : Wr[(size_t)(k-KH)*HID + c];
    v[j] = f2bf(w);
  }
  uint4 o;
  o.x = ((unsigned)v[1]<<16)|v[0]; o.y = ((unsigned)v[3]<<16)|v[2];
  o.z = ((unsigned)v[5]<<16)|v[4]; o.w = ((unsigned)v[7]<<16)|v[6];
  ((uint4*)Bp)[id] = o;
}

// ---------------- mean aggregation: gather H-part of F, write agg-part ----------------
template<int KH>   // features per part; F row stride = 2*KH
__global__ __launch_bounds__(256) void k_agg(unsigned short* __restrict__ F, const int* __restrict__ eidx,
                      const int* __restrict__ rowptr, const float* __restrict__ invdeg){
  const int F8 = KH/8;     // lanes per row (8 or 16)
  const int RPI = 64/F8;   // rows per wave-iter (8 or 4)
  const int KS = 2*KH;
  int wave = threadIdx.x >> 6;
  int lane = threadIdx.x & 63;
  int n = blockIdx.x*4 + wave;
  int b = rowptr[n], e = rowptr[n+1];
  int r = lane / F8, q = lane % F8;
  float acc[8] = {0,0,0,0,0,0,0,0};
  for(int i = b + r; i < e; i += RPI){
    int s = eidx[i];
    uint4 u = *(const uint4*)(F + (size_t)s*KS + KH + q*8);
    acc[0] += bflo(u.x); acc[1] += bfhi(u.x);
    acc[2] += bflo(u.y); acc[3] += bfhi(u.y);
    acc[4] += bflo(u.z); acc[5] += bfhi(u.z);
    acc[6] += bflo(u.w); acc[7] += bfhi(u.w);
  }
  #pragma unroll
  for(int off = F8; off < 64; off <<= 1){
    #pragma unroll
    for(int k=0;k<8;k++) acc[k] += __shfl_xor(acc[k], off, 64);
  }
  if(lane < F8){
    float id = invdeg[n];
    uint4 o;
    o.x = fpack(acc[0]*id, acc[1]*id); o.y = fpack(acc[2]*id, acc[3]*id);
    o.z = fpack(acc[4]*id, acc[5]*id); o.w = fpack(acc[6]*id, acc[7]*id);
    *(uint4*)(F + (size_t)n*KS + q*8) = o;
  }
}

// ---------------- MFMA GEMM: raw = F @ [Wn;Wr] + b, with col-stats epilogue ----------------
template<int K>   // 128 (layer0) or 256
__global__ __launch_bounds__(256) void k_gemm(const unsigned short* __restrict__ F,
                     const unsigned short* __restrict__ Bp, const float* __restrict__ bias,
                     unsigned short* __restrict__ raw,
                     float* __restrict__ psum, float* __restrict__ psq){
  const int NKS = K/32;
  int wave = threadIdx.x>>6, lane = threadIdx.x&63;
  int row0w = blockIdx.x*64 + wave*16;
  if(row0w >= N_NODES) return;           // 50000 % 16 == 0: tiles fully valid or fully invalid
  int m = lane&15, quad = lane>>4;
  const unsigned short* Arow = F + (size_t)(row0w+m)*K + quad*8;
  f32x4 acc[8];
  #pragma unroll
  for(int nt=0;nt<8;nt++) acc[nt] = (f32x4){0.f,0.f,0.f,0.f};
  #pragma unroll 1
  for(int ks=0; ks<NKS; ks++){
    bf16x8 a = *(const bf16x8*)(Arow + ks*32);
    const unsigned short* bp = Bp + ((size_t)ks*64 + lane)*8;
    #pragma unroll
    for(int nt=0;nt<8;nt++){
      bf16x8 b = *(const bf16x8*)(bp + (size_t)nt*NKS*64*8);
      acc[nt] = __builtin_amdgcn_mfma_f32_16x16x32_bf16(a, b, acc[nt], 0, 0, 0);
    }
  }
  int sp = blockIdx.x & (SPREAD-1);
  #pragma unroll
  for(int nt=0;nt<8;nt++){
    int col = nt*16 + m;
    float bv = bias[col];
    float s = 0.f, s2 = 0.f;
    #pragma unroll
    for(int reg=0;reg<4;reg++){
      float v = acc[nt][reg] + bv;
      int row = row0w + quad*4 + reg;
      raw[(size_t)row*HID + col] = f2bf(v);
      s += v; s2 += v*v;
    }
    s  += __shfl_xor(s, 16, 64);  s  += __shfl_xor(s, 32, 64);
    s2 += __shfl_xor(s2, 16, 64); s2 += __shfl_xor(s2, 32, 64);
    if(quad==0){
      atomicAdd(&psum[sp*HID+col], s);
      atomicAdd(&psq [sp*HID+col], s2);
    }
  }
}

// ---------------- reduce spread col-stats -> scale/shift ----------------
__global__ void k_bnfinal(const float* __restrict__ psum, const float* __restrict__ psq,
                          const float* __restrict__ gamma, const float* __restrict__ beta,
                          float* __restrict__ scale, float* __restrict__ shift){
  int t = threadIdx.x;
  float s = 0.f, s2 = 0.f;
  for(int i=0;i<SPREAD;i++){ s += psum[i*HID+t]; s2 += psq[i*HID+t]; }
  float mu  = s  * (1.0f/(float)N_NODES);
  float var = s2 * (1.0f/(float)N_NODES) - mu*mu;
  float rstd = rsqrtf(var + BN_EPS);
  float sc = rstd * gamma[t];
  scale[t] = sc;
  shift[t] = beta[t] - mu*sc;
}

// ---------------- apply BN+ReLU: raw(bf16) -> F_next H-part (bf16, row stride 256) ----------------
__global__ __launch_bounds__(256) void k_transform(const unsigned short* __restrict__ raw,
                     const float* __restrict__ scale, const float* __restrict__ shift,
                     unsigned short* __restrict__ Fn){
  int tid = blockIdx.x*256 + threadIdx.x;  // 50000*16
  if(tid >= N_NODES*16) return;
  int row = tid>>4, q = tid&15;
  uint4 u = ((const uint4*)raw)[(size_t)row*16 + q];
  float4 sc0 = ((const float4*)scale)[q*2], sc1 = ((const float4*)scale)[q*2+1];
  float4 sf0 = ((const float4*)shift)[q*2], sf1 = ((const float4*)shift)[q*2+1];
  float f0 = fmaxf(fmaf(bflo(u.x), sc0.x, sf0.x), 0.f);
  float f1 = fmaxf(fmaf(bfhi(u.x), sc0.y, sf0.y), 0.f);
  float f2 = fmaxf(fmaf(bflo(u.y), sc0.z, sf0.z), 0.f);
  float f3 = fmaxf(fmaf(bfhi(u.y), sc0.w, sf0.w), 0.f);
  float f4 = fmaxf(fmaf(bflo(u.z), sc1.x, sf1.x), 0.f);
  float f5 = fmaxf(fmaf(bfhi(u.z), sc1.y, sf1.y), 0.f);
  float f6 = fmaxf(fmaf(bflo(u.w), sc1.z, sf1.z), 0.f);
  float f7 = fmaxf(fmaf(bfhi(u.w), sc1.w, sf1.w), 0.f);
  uint4 o;
  o.x = fpack(f0,f1); o.y = fpack(f2,f3); o.z = fpack(f4,f5); o.w = fpack(f6,f7);
  ((uint4*)Fn)[(size_t)row*32 + 16 + q] = o;   // row stride 256 bf16 = 32 uint4; H at col 128
}

// ---------------- global mean pool (batch sorted; applies BN2+ReLU) ----------------
__global__ void k_pool(const unsigned short* __restrict__ raw, const int* __restrict__ batch,
                       const float* __restrict__ scale, const float* __restrict__ shift,
                       float* __restrict__ pooled, float* __restrict__ cnt){
  const int CH = 32;
  int f = threadIdx.x;
  float sc = scale[f], sf = shift[f];
  int n0 = blockIdx.x * CH;
  int nEnd = min(n0+CH, N_NODES);
  float acc = 0.f; int cur = -1; int c = 0;
  for(int n=n0;n<nEnd;n++){
    int b = batch[n];
    if(b != cur){
      if(cur >= 0){
        atomicAdd(&pooled[cur*HID+f], acc);
        if(f==0) atomicAdd(&cnt[cur], (float)c);
      }
      acc = 0.f; c = 0; cur = b;
    }
    float v = bf2f(raw[(size_t)n*HID + f]);
    acc += fmaxf(fmaf(v, sc, sf), 0.f);
    c++;
  }
  if(cur >= 0){
    atomicAdd(&pooled[cur*HID+f], acc);
    if(f==0) atomicAdd(&cnt[cur], (float)c);
  }
}

// ---------------- MLP head: one wave per graph ----------------
__global__ void k_mlp(const float* __restrict__ pooled, const float* __restrict__ cnt,
                      const float* __restrict__ fc1W, const float* __restrict__ fc1b,
                      const float* __restrict__ fc2W, const float* __restrict__ fc2b,
                      float* __restrict__ out){
  __shared__ float p[HID];
  int g = blockIdx.x; int t = threadIdx.x;
  float ic = 1.0f / fmaxf(cnt[g], 1.0f);
  p[t]      = pooled[g*HID + t]      * ic;
  p[t + 64] = pooled[g*HID + t + 64] * ic;
  __syncthreads();
  float z = fc1b[t];
  #pragma unroll 4
  for(int k=0;k<HID;k++) z += p[k]*fc1W[k*64 + t];
  z = fmaxf(z, 0.f);
  float v = z * fc2W[t];
  #pragma unroll
  for(int off=32; off>0; off>>=1) v += __shfl_down(v, off, 64);
  if(t==0) out[g] = 1.0f/(1.0f + expf(-(v + fc2b[0])));
}

extern "C" void kernel_launch(void* const* d_in, const int* in_sizes, int n_in,
                              void* d_out, int out_size, void* d_ws, size_t ws_size,
                              hipStream_t stream){
  const float* x    = (const float*)d_in[0];
  const int*   ei   = (const int*)d_in[1];
  const int*   batch= (const int*)d_in[2];
  const float* Wn0=(const float*)d_in[3]; const float* Wr0=(const float*)d_in[4]; const float* b0=(const float*)d_in[5];
  const float* Wn1=(const float*)d_in[6]; const float* Wr1=(const float*)d_in[7]; const float* b1=(const float*)d_in[8];
  const float* Wn2=(const float*)d_in[9]; const float* Wr2=(const float*)d_in[10]; const float* b2=(const float*)d_in[11];
  const float* gamma=(const float*)d_in[12]; const float* beta=(const float*)d_in[13];
  const float* fc1W=(const float*)d_in[14]; const float* fc1b=(const float*)d_in[15];
  const float* fc2W=(const float*)d_in[16]; const float* fc2b=(const float*)d_in[17];
  float* out = (float*)d_out;

  char* ws = (char*)d_ws;
  size_t off = 0;
  auto alloc = [&](size_t bytes)->char*{ char* p = ws + off; off += (bytes + 255) & ~(size_t)255; return p; };

  // --- zeroed region (single memset): degcnt | pstats | pooled+cnt ---
  char* zero0   = ws + off;
  int*   degcnt = (int*)alloc((size_t)N_NODES*4);
  float* pstats = (float*)alloc((size_t)3*2*SPREAD*HID*4);
  float* pooled = (float*)alloc(((size_t)NUM_GRAPHS*HID + NUM_GRAPHS)*4);
  float* cnt    = pooled + (size_t)NUM_GRAPHS*HID;
  size_t zbytes = (size_t)((ws + off) - zero0);

  // --- non-zeroed scratch ---
  unsigned short* F0  = (unsigned short*)alloc((size_t)N_NODES*128*2);  // [agg64|x64] bf16
  unsigned short* F1  = (unsigned short*)alloc((size_t)N_NODES*256*2);  // [agg128|h128]
  unsigned short* F2  = (unsigned short*)alloc((size_t)N_NODES*256*2);
  unsigned short* raw = (unsigned short*)alloc((size_t)N_NODES*HID*2);  // reused each layer
  unsigned short* Bp0 = (unsigned short*)alloc((size_t)8*4*64*8*2);     // K=128
  unsigned short* Bp1 = (unsigned short*)alloc((size_t)8*8*64*8*2);     // K=256
  unsigned short* Bp2 = (unsigned short*)alloc((size_t)8*8*64*8*2);
  float* invdeg = (float*)alloc((size_t)N_NODES*4);
  int* rowptr   = (int*)alloc((size_t)(N_NODES+1)*4);
  int* fill     = (int*)alloc((size_t)N_NODES*4);
  int* eidx     = (int*)alloc((size_t)N_EDGES*4);
  int* blocksum = (int*)alloc((size_t)SB*4);
  int* blockpre = (int*)alloc((size_t)SB*4);
  float* ss     = (float*)alloc((size_t)3*2*HID*4);

  auto psumL = [&](int l){ return pstats + (size_t)l*2*SPREAD*HID; };
  auto psqL  = [&](int l){ return pstats + (size_t)l*2*SPREAD*HID + (size_t)SPREAD*HID; };
  auto scaleL= [&](int l){ return ss + (size_t)l*2*HID; };
  auto shiftL= [&](int l){ return ss + (size_t)l*2*HID + HID; };

  const int* src = ei;
  const int* dst = ei + N_EDGES;

  hipMemsetAsync(zero0, 0, zbytes, stream);

  // CSR build
  k_count<<<(N_EDGES+255)/256, 256, 0, stream>>>(dst, degcnt);
  k_scanA<<<SB, 256, 0, stream>>>(degcnt, blocksum);
  k_scanB<<<1, 128, 0, stream>>>(blocksum, blockpre, rowptr);
  k_scanC<<<SB, 256, 0, stream>>>(degcnt, blockpre, rowptr, fill, invdeg);
  k_fill<<<(N_EDGES+255)/256, 256, 0, stream>>>(src, dst, fill, eidx);

  // packs
  k_packX<<<(N_NODES*8+255)/256, 256, 0, stream>>>(x, F0);
  k_packW<IN_DIM><<<(8*4*64+255)/256, 256, 0, stream>>>(Wn0, Wr0, Bp0);
  k_packW<HID><<<(8*8*64+255)/256, 256, 0, stream>>>(Wn1, Wr1, Bp1);
  k_packW<HID><<<(8*8*64+255)/256, 256, 0, stream>>>(Wn2, Wr2, Bp2);

  const int GEMM_BLKS = (N_NODES + 63)/64;   // 782

  // ---- layer 0 ----
  k_agg<IN_DIM><<<N_NODES/4, 256, 0, stream>>>(F0, eidx, rowptr, invdeg);
  k_gemm<128><<<GEMM_BLKS, 256, 0, stream>>>(F0, Bp0, b0, raw, psumL(0), psqL(0));
  k_bnfinal<<<1, 128, 0, stream>>>(psumL(0), psqL(0), gamma+0*HID, beta+0*HID, scaleL(0), shiftL(0));
  k_transform<<<(N_NODES*16+255)/256, 256, 0, stream>>>(raw, scaleL(0), shiftL(0), F1);

  // ---- layer 1 ----
  k_agg<HID><<<N_NODES/4, 256, 0, stream>>>(F1, eidx, rowptr, invdeg);
  k_gemm<256><<<GEMM_BLKS, 256, 0, stream>>>(F1, Bp1, b1, raw, psumL(1), psqL(1));
  k_bnfinal<<<1, 128, 0, stream>>>(psumL(1), psqL(1), gamma+1*HID, beta+1*HID, scaleL(1), shiftL(1));
  k_transform<<<(N_NODES*16+255)/256, 256, 0, stream>>>(raw, scaleL(1), shiftL(1), F2);

  // ---- layer 2 ----
  k_agg<HID><<<N_NODES/4, 256, 0, stream>>>(F2, eidx, rowptr, invdeg);
  k_gemm<256><<<GEMM_BLKS, 256, 0, stream>>>(F2, Bp2, b2, raw, psumL(2), psqL(2));
  k_bnfinal<<<1, 128, 0, stream>>>(psumL(2), psqL(2), gamma+2*HID, beta+2*HID, scaleL(2), shiftL(2));

  // ---- pool (applies BN2+ReLU) + MLP head ----
  k_pool<<<(N_NODES+31)/32, 128, 0, stream>>>(raw, batch, scaleL(2), shiftL(2), pooled, cnt);
  k_mlp<<<NUM_GRAPHS, 64, 0, stream>>>(pooled, cnt, fc1W, fc1b, fc2W, fc2b, out);
}

// Round 4
// 329.913 us; speedup vs baseline: 3.0285x; 1.1725x over previous
//
#include <hip/hip_runtime.h>

#define N_NODES 50000
#define N_EDGES 800000
#define NUM_GRAPHS 256
#define HID 128
#define IN_DIM 64
#define BN_EPS 1e-5f
#define SPREAD 64
#define NB 196            // buckets: dst>>8, 49999>>8 = 195
#define BUCKET 256        // nodes per bucket
#define SCHUNK 4096       // edges per scatter block

typedef __attribute__((ext_vector_type(8))) short bf16x8;
typedef __attribute__((ext_vector_type(4))) float f32x4;

// ---- bf16 helpers (storage = ushort) ----
__device__ __forceinline__ float bf2f(unsigned short u){ union{unsigned i;float f;}c; c.i=((unsigned)u)<<16; return c.f; }
__device__ __forceinline__ float bflo(unsigned w){ union{unsigned i;float f;}c; c.i=w<<16; return c.f; }
__device__ __forceinline__ float bfhi(unsigned w){ union{unsigned i;float f;}c; c.i=w&0xFFFF0000u; return c.f; }
__device__ __forceinline__ unsigned short f2bf(float f){ union{float f;unsigned i;}c; c.f=f; unsigned r=c.i+0x7FFF+((c.i>>16)&1); return (unsigned short)(r>>16); }
__device__ __forceinline__ unsigned fpack(float a, float b){ // a->low16, b->high16 (RNE)
  union{float f;unsigned i;}ca,cb; ca.f=a; cb.f=b;
  unsigned ra=((ca.i+0x7FFF+((ca.i>>16)&1))>>16)&0xFFFFu;
  unsigned rb=(cb.i+0x7FFF+((cb.i>>16)&1))&0xFFFF0000u;
  return ra|rb;
}

// ---------------- CSR build (bucketed, write-coalesced) ----------------
// 1) histogram of 196 dst-buckets
__global__ __launch_bounds__(256) void k_hist(const int* __restrict__ dst, int* __restrict__ bcount){
  __shared__ int h[NB];
  int t = threadIdx.x;
  for(int i=t;i<NB;i+=256) h[i]=0;
  __syncthreads();
  int base = blockIdx.x*SCHUNK;
  int n = min(SCHUNK, N_EDGES-base);
  for(int v=t; v<n; v+=256) atomicAdd(&h[dst[base+v]>>8], 1);
  __syncthreads();
  for(int i=t;i<NB;i+=256) if(h[i]) atomicAdd(&bcount[i], h[i]);
}

// 2) scan 196 bucket counts -> bases + fill cursors
__global__ __launch_bounds__(256) void k_bucketscan(const int* __restrict__ bcount, int* __restrict__ bbase,
                                                    int* __restrict__ bfill, int* __restrict__ rowptr){
  __shared__ int sh[256];
  int t = threadIdx.x;
  int v = (t<NB)? bcount[t] : 0;
  sh[t]=v; __syncthreads();
  for(int off=1;off<256;off<<=1){ int u=(t>=off)?sh[t-off]:0; __syncthreads(); sh[t]+=u; __syncthreads(); }
  if(t<NB){ bbase[t]=sh[t]-v; bfill[t]=sh[t]-v; }
  if(t==0){ bbase[NB]=N_EDGES; rowptr[N_NODES]=N_EDGES; }
}

// 3) LDS-staged scatter of (src,dst) pairs into bucket-grouped order (unstable; coalesced runs)
__global__ __launch_bounds__(256) void k_bscatter(const int* __restrict__ src, const int* __restrict__ dst,
                                                  int* __restrict__ bfill, uint2* __restrict__ pairs){
  __shared__ int h[NB], lbase[NB], gbase[NB], cur[NB];
  __shared__ int sc[256];
  __shared__ uint2 staged[SCHUNK];
  int t = threadIdx.x;
  for(int i=t;i<NB;i+=256) h[i]=0;
  __syncthreads();
  int base = blockIdx.x*SCHUNK;
  int n = min(SCHUNK, N_EDGES-base);
  for(int v=t; v<n; v+=256) atomicAdd(&h[dst[base+v]>>8], 1);
  __syncthreads();
  int hv = (t<NB)? h[t] : 0;
  sc[t]=hv; __syncthreads();
  for(int off=1;off<256;off<<=1){ int u=(t>=off)?sc[t-off]:0; __syncthreads(); sc[t]+=u; __syncthreads(); }
  if(t<NB){ lbase[t]=sc[t]-hv; cur[t]=0; if(hv) gbase[t]=atomicAdd(&bfill[t], hv); }
  __syncthreads();
  for(int v=t; v<n; v+=256){
    int s = src[base+v], d = dst[base+v];     // L2-hot re-read
    int b = d>>8;
    int r = atomicAdd(&cur[b], 1);
    staged[lbase[b]+r] = make_uint2((unsigned)s,(unsigned)d);
  }
  __syncthreads();
  for(int i=t; i<n; i+=256){
    uint2 p = staged[i];
    int b = (int)(p.y>>8);
    pairs[gbase[b] + (i - lbase[b])] = p;     // coalesced runs (~21 pairs)
  }
}

// 4) per-bucket exact CSR: rowptr, invdeg, eidx (writes confined to bucket's region)
__global__ __launch_bounds__(1024) void k_csr(const uint2* __restrict__ pairs, const int* __restrict__ bbase,
                                              int* __restrict__ rowptr, float* __restrict__ invdeg,
                                              int* __restrict__ eidx){
  __shared__ int cnt[BUCKET], cur[BUCKET], sc[BUCKET];
  int t = threadIdx.x;
  int b = blockIdx.x;
  int node0 = b*BUCKET;
  int nn = min(BUCKET, N_NODES-node0);
  if(t<BUCKET) cnt[t]=0;
  __syncthreads();
  int e0 = bbase[b], e1 = bbase[b+1];
  for(int i=e0+t; i<e1; i+=1024) atomicAdd(&cnt[(int)pairs[i].y - node0], 1);
  __syncthreads();
  if(t<BUCKET) sc[t]=cnt[t];
  __syncthreads();
  for(int off=1;off<BUCKET;off<<=1){
    int u=0;
    if(t<BUCKET && t>=off) u=sc[t-off];
    __syncthreads();
    if(t<BUCKET) sc[t]+=u;
    __syncthreads();
  }
  if(t<nn){
    int pre = sc[t]-cnt[t] + e0;
    rowptr[node0+t] = pre;
    cur[t] = pre;
    invdeg[node0+t] = 1.0f/(float)max(cnt[t],1);
  }
  __syncthreads();
  for(int i=e0+t; i<e1; i+=1024){
    uint2 p = pairs[i];
    int pos = atomicAdd(&cur[(int)p.y - node0], 1);
    eidx[pos] = (int)p.x;
  }
}

// ---------------- pack x (fp32) -> F0 H-part (bf16) ----------------
__global__ __launch_bounds__(256) void k_packX(const float* __restrict__ x, unsigned short* __restrict__ F0){
  int tid = blockIdx.x*256 + threadIdx.x;   // 50000*8
  if(tid >= N_NODES*8) return;
  int row = tid>>3, q = tid&7;
  float4 a = ((const float4*)x)[(size_t)row*16 + q*2];
  float4 b = ((const float4*)x)[(size_t)row*16 + q*2 + 1];
  uint4 o;
  o.x = fpack(a.x, a.y); o.y = fpack(a.z, a.w);
  o.z = fpack(b.x, b.y); o.w = fpack(b.z, b.w);
  ((uint4*)F0)[(size_t)row*16 + 8 + q] = o;   // F0 row stride 128 bf16 = 16 uint4; H at col 64
}

// ---------------- pack weights into MFMA B-frag order ----------------
template<int KH>
__global__ __launch_bounds__(256) void k_packW(const float* __restrict__ Wn, const float* __restrict__ Wr,
                                               unsigned short* __restrict__ Bp){
  const int NKS = (2*KH)/32;
  int id = blockIdx.x*256 + threadIdx.x;
  if(id >= 8*NKS*64) return;
  int lane = id & 63;
  int ks = (id>>6) % NKS;
  int nt = (id>>6) / NKS;
  int quad = lane>>4, m = lane&15;
  int c = nt*16 + m;
  unsigned short v[8];
  #pragma unroll
  for(int j=0;j<8;j++){
    int k = ks*32 + quad*8 + j;
    float w = (k < KH) ? Wn[(size_t)k*HID + c] : Wr[(size_t)(k-KH)*HID + c];
    v[j] = f2bf(w);
  }
  uint4 o;
  o.x = ((unsigned)v[1]<<16)|v[0]; o.y = ((unsigned)v[3]<<16)|v[2];
  o.z = ((unsigned)v[5]<<16)|v[4]; o.w = ((unsigned)v[7]<<16)|v[6];
  ((uint4*)Bp)[id] = o;
}

// ---------------- mean aggregation: gather H-part of F, write agg-part ----------------
template<int KH>   // features per part; F row stride = 2*KH
__global__ __launch_bounds__(256) void k_agg(unsigned short* __restrict__ F, const int* __restrict__ eidx,
                      const int* __restrict__ rowptr, const float* __restrict__ invdeg){
  const int F8 = KH/8;
  const int RPI = 64/F8;
  const int KS = 2*KH;
  int wave = threadIdx.x >> 6;
  int lane = threadIdx.x & 63;
  int n = blockIdx.x*4 + wave;
  int b = rowptr[n], e = rowptr[n+1];
  int r = lane / F8, q = lane % F8;
  float acc[8] = {0,0,0,0,0,0,0,0};
  for(int i = b + r; i < e; i += RPI){
    int s = eidx[i];
    uint4 u = *(const uint4*)(F + (size_t)s*KS + KH + q*8);
    acc[0] += bflo(u.x); acc[1] += bfhi(u.x);
    acc[2] += bflo(u.y); acc[3] += bfhi(u.y);
    acc[4] += bflo(u.z); acc[5] += bfhi(u.z);
    acc[6] += bflo(u.w); acc[7] += bfhi(u.w);
  }
  #pragma unroll
  for(int off = F8; off < 64; off <<= 1){
    #pragma unroll
    for(int k=0;k<8;k++) acc[k] += __shfl_xor(acc[k], off, 64);
  }
  if(lane < F8){
    float id = invdeg[n];
    uint4 o;
    o.x = fpack(acc[0]*id, acc[1]*id); o.y = fpack(acc[2]*id, acc[3]*id);
    o.z = fpack(acc[4]*id, acc[5]*id); o.w = fpack(acc[6]*id, acc[7]*id);
    *(uint4*)(F + (size_t)n*KS + q*8) = o;
  }
}

// ---------------- MFMA GEMM: raw = F @ [Wn;Wr] + b, with col-stats epilogue ----------------
template<int K>   // 128 (layer0) or 256
__global__ __launch_bounds__(256) void k_gemm(const unsigned short* __restrict__ F,
                     const unsigned short* __restrict__ Bp, const float* __restrict__ bias,
                     unsigned short* __restrict__ raw,
                     float* __restrict__ psum, float* __restrict__ psq){
  const int NKS = K/32;
  int wave = threadIdx.x>>6, lane = threadIdx.x&63;
  int row0w = blockIdx.x*64 + wave*16;
  if(row0w >= N_NODES) return;
  int m = lane&15, quad = lane>>4;
  const unsigned short* Arow = F + (size_t)(row0w+m)*K + quad*8;
  f32x4 acc[8];
  #pragma unroll
  for(int nt=0;nt<8;nt++) acc[nt] = (f32x4){0.f,0.f,0.f,0.f};
  #pragma unroll 1
  for(int ks=0; ks<NKS; ks++){
    bf16x8 a = *(const bf16x8*)(Arow + ks*32);
    const unsigned short* bp = Bp + ((size_t)ks*64 + lane)*8;
    #pragma unroll
    for(int nt=0;nt<8;nt++){
      bf16x8 b = *(const bf16x8*)(bp + (size_t)nt*NKS*64*8);
      acc[nt] = __builtin_amdgcn_mfma_f32_16x16x32_bf16(a, b, acc[nt], 0, 0, 0);
    }
  }
  int sp = blockIdx.x & (SPREAD-1);
  #pragma unroll
  for(int nt=0;nt<8;nt++){
    int col = nt*16 + m;
    float bv = bias[col];
    float s = 0.f, s2 = 0.f;
    #pragma unroll
    for(int reg=0;reg<4;reg++){
      float v = acc[nt][reg] + bv;
      int row = row0w + quad*4 + reg;
      raw[(size_t)row*HID + col] = f2bf(v);
      s += v; s2 += v*v;
    }
    s  += __shfl_xor(s, 16, 64);  s  += __shfl_xor(s, 32, 64);
    s2 += __shfl_xor(s2, 16, 64); s2 += __shfl_xor(s2, 32, 64);
    if(quad==0){
      atomicAdd(&psum[sp*HID+col], s);
      atomicAdd(&psq [sp*HID+col], s2);
    }
  }
}

// ---------------- reduce spread col-stats -> scale/shift ----------------
__global__ void k_bnfinal(const float* __restrict__ psum, const float* __restrict__ psq,
                          const float* __restrict__ gamma, const float* __restrict__ beta,
                          float* __restrict__ scale, float* __restrict__ shift){
  int t = threadIdx.x;
  float s = 0.f, s2 = 0.f;
  for(int i=0;i<SPREAD;i++){ s += psum[i*HID+t]; s2 += psq[i*HID+t]; }
  float mu  = s  * (1.0f/(float)N_NODES);
  float var = s2 * (1.0f/(float)N_NODES) - mu*mu;
  float rstd = rsqrtf(var + BN_EPS);
  float sc = rstd * gamma[t];
  scale[t] = sc;
  shift[t] = beta[t] - mu*sc;
}

// ---------------- apply BN+ReLU: raw(bf16) -> F_next H-part ----------------
__global__ __launch_bounds__(256) void k_transform(const unsigned short* __restrict__ raw,
                     const float* __restrict__ scale, const float* __restrict__ shift,
                     unsigned short* __restrict__ Fn){
  int tid = blockIdx.x*256 + threadIdx.x;  // 50000*16
  if(tid >= N_NODES*16) return;
  int row = tid>>4, q = tid&15;
  uint4 u = ((const uint4*)raw)[(size_t)row*16 + q];
  float4 sc0 = ((const float4*)scale)[q*2], sc1 = ((const float4*)scale)[q*2+1];
  float4 sf0 = ((const float4*)shift)[q*2], sf1 = ((const float4*)shift)[q*2+1];
  float f0 = fmaxf(fmaf(bflo(u.x), sc0.x, sf0.x), 0.f);
  float f1 = fmaxf(fmaf(bfhi(u.x), sc0.y, sf0.y), 0.f);
  float f2 = fmaxf(fmaf(bflo(u.y), sc0.z, sf0.z), 0.f);
  float f3 = fmaxf(fmaf(bfhi(u.y), sc0.w, sf0.w), 0.f);
  float f4 = fmaxf(fmaf(bflo(u.z), sc1.x, sf1.x), 0.f);
  float f5 = fmaxf(fmaf(bfhi(u.z), sc1.y, sf1.y), 0.f);
  float f6 = fmaxf(fmaf(bflo(u.w), sc1.z, sf1.z), 0.f);
  float f7 = fmaxf(fmaf(bfhi(u.w), sc1.w, sf1.w), 0.f);
  uint4 o;
  o.x = fpack(f0,f1); o.y = fpack(f2,f3); o.z = fpack(f4,f5); o.w = fpack(f6,f7);
  ((uint4*)Fn)[(size_t)row*32 + 16 + q] = o;
}

// ---------------- global mean pool (batch sorted; applies BN2+ReLU) ----------------
__global__ void k_pool(const unsigned short* __restrict__ raw, const int* __restrict__ batch,
                       const float* __restrict__ scale, const float* __restrict__ shift,
                       float* __restrict__ pooled, float* __restrict__ cnt){
  const int CH = 32;
  int f = threadIdx.x;
  float sc = scale[f], sf = shift[f];
  int n0 = blockIdx.x * CH;
  int nEnd = min(n0+CH, N_NODES);
  float acc = 0.f; int cur = -1; int c = 0;
  for(int n=n0;n<nEnd;n++){
    int b = batch[n];
    if(b != cur){
      if(cur >= 0){
        atomicAdd(&pooled[cur*HID+f], acc);
        if(f==0) atomicAdd(&cnt[cur], (float)c);
      }
      acc = 0.f; c = 0; cur = b;
    }
    float v = bf2f(raw[(size_t)n*HID + f]);
    acc += fmaxf(fmaf(v, sc, sf), 0.f);
    c++;
  }
  if(cur >= 0){
    atomicAdd(&pooled[cur*HID+f], acc);
    if(f==0) atomicAdd(&cnt[cur], (float)c);
  }
}

// ---------------- MLP head: one wave per graph ----------------
__global__ void k_mlp(const float* __restrict__ pooled, const float* __restrict__ cnt,
                      const float* __restrict__ fc1W, const float* __restrict__ fc1b,
                      const float* __restrict__ fc2W, const float* __restrict__ fc2b,
                      float* __restrict__ out){
  __shared__ float p[HID];
  int g = blockIdx.x; int t = threadIdx.x;
  float ic = 1.0f / fmaxf(cnt[g], 1.0f);
  p[t]      = pooled[g*HID + t]      * ic;
  p[t + 64] = pooled[g*HID + t + 64] * ic;
  __syncthreads();
  float z = fc1b[t];
  #pragma unroll 4
  for(int k=0;k<HID;k++) z += p[k]*fc1W[k*64 + t];
  z = fmaxf(z, 0.f);
  float v = z * fc2W[t];
  #pragma unroll
  for(int off=32; off>0; off>>=1) v += __shfl_down(v, off, 64);
  if(t==0) out[g] = 1.0f/(1.0f + expf(-(v + fc2b[0])));
}

extern "C" void kernel_launch(void* const* d_in, const int* in_sizes, int n_in,
                              void* d_out, int out_size, void* d_ws, size_t ws_size,
                              hipStream_t stream){
  const float* x    = (const float*)d_in[0];
  const int*   ei   = (const int*)d_in[1];
  const int*   batch= (const int*)d_in[2];
  const float* Wn0=(const float*)d_in[3]; const float* Wr0=(const float*)d_in[4]; const float* b0=(const float*)d_in[5];
  const float* Wn1=(const float*)d_in[6]; const float* Wr1=(const float*)d_in[7]; const float* b1=(const float*)d_in[8];
  const float* Wn2=(const float*)d_in[9]; const float* Wr2=(const float*)d_in[10]; const float* b2=(const float*)d_in[11];
  const float* gamma=(const float*)d_in[12]; const float* beta=(const float*)d_in[13];
  const float* fc1W=(const float*)d_in[14]; const float* fc1b=(const float*)d_in[15];
  const float* fc2W=(const float*)d_in[16]; const float* fc2b=(const float*)d_in[17];
  float* out = (float*)d_out;

  char* ws = (char*)d_ws;
  size_t off = 0;
  auto alloc = [&](size_t bytes)->char*{ char* p = ws + off; off += (bytes + 255) & ~(size_t)255; return p; };

  // --- zeroed region (single memset): bcount | pstats | pooled+cnt ---
  char* zero0   = ws + off;
  int*   bcount = (int*)alloc((size_t)NB*4);
  float* pstats = (float*)alloc((size_t)3*2*SPREAD*HID*4);
  float* pooled = (float*)alloc(((size_t)NUM_GRAPHS*HID + NUM_GRAPHS)*4);
  float* cnt    = pooled + (size_t)NUM_GRAPHS*HID;
  size_t zbytes = (size_t)((ws + off) - zero0);

  // --- non-zeroed scratch ---
  unsigned short* F0  = (unsigned short*)alloc((size_t)N_NODES*128*2);  // [agg64|x64] bf16
  unsigned short* F1  = (unsigned short*)alloc((size_t)N_NODES*256*2);  // [agg128|h128]
  unsigned short* F2  = (unsigned short*)alloc((size_t)N_NODES*256*2);
  unsigned short* raw = (unsigned short*)alloc((size_t)N_NODES*HID*2);
  unsigned short* Bp0 = (unsigned short*)alloc((size_t)8*4*64*8*2);     // K=128
  unsigned short* Bp1 = (unsigned short*)alloc((size_t)8*8*64*8*2);     // K=256
  unsigned short* Bp2 = (unsigned short*)alloc((size_t)8*8*64*8*2);
  float* invdeg = (float*)alloc((size_t)N_NODES*4);
  int* rowptr   = (int*)alloc((size_t)(N_NODES+1)*4);
  int* eidx     = (int*)alloc((size_t)N_EDGES*4);
  uint2* pairs  = (uint2*)alloc((size_t)N_EDGES*8);
  int* bbase    = (int*)alloc((size_t)(NB+1)*4);
  int* bfill    = (int*)alloc((size_t)NB*4);
  float* ss     = (float*)alloc((size_t)3*2*HID*4);

  auto psumL = [&](int l){ return pstats + (size_t)l*2*SPREAD*HID; };
  auto psqL  = [&](int l){ return pstats + (size_t)l*2*SPREAD*HID + (size_t)SPREAD*HID; };
  auto scaleL= [&](int l){ return ss + (size_t)l*2*HID; };
  auto shiftL= [&](int l){ return ss + (size_t)l*2*HID + HID; };

  const int* src = ei;
  const int* dst = ei + N_EDGES;

  hipMemsetAsync(zero0, 0, zbytes, stream);

  // CSR build (bucketed)
  const int NCHUNK = (N_EDGES + SCHUNK - 1)/SCHUNK;   // 196
  k_hist<<<NCHUNK, 256, 0, stream>>>(dst, bcount);
  k_bucketscan<<<1, 256, 0, stream>>>(bcount, bbase, bfill, rowptr);
  k_bscatter<<<NCHUNK, 256, 0, stream>>>(src, dst, bfill, pairs);
  k_csr<<<NB, 1024, 0, stream>>>(pairs, bbase, rowptr, invdeg, eidx);

  // packs
  k_packX<<<(N_NODES*8+255)/256, 256, 0, stream>>>(x, F0);
  k_packW<IN_DIM><<<(8*4*64+255)/256, 256, 0, stream>>>(Wn0, Wr0, Bp0);
  k_packW<HID><<<(8*8*64+255)/256, 256, 0, stream>>>(Wn1, Wr1, Bp1);
  k_packW<HID><<<(8*8*64+255)/256, 256, 0, stream>>>(Wn2, Wr2, Bp2);

  const int GEMM_BLKS = (N_NODES + 63)/64;   // 782

  // ---- layer 0 ----
  k_agg<IN_DIM><<<N_NODES/4, 256, 0, stream>>>(F0, eidx, rowptr, invdeg);
  k_gemm<128><<<GEMM_BLKS, 256, 0, stream>>>(F0, Bp0, b0, raw, psumL(0), psqL(0));
  k_bnfinal<<<1, 128, 0, stream>>>(psumL(0), psqL(0), gamma+0*HID, beta+0*HID, scaleL(0), shiftL(0));
  k_transform<<<(N_NODES*16+255)/256, 256, 0, stream>>>(raw, scaleL(0), shiftL(0), F1);

  // ---- layer 1 ----
  k_agg<HID><<<N_NODES/4, 256, 0, stream>>>(F1, eidx, rowptr, invdeg);
  k_gemm<256><<<GEMM_BLKS, 256, 0, stream>>>(F1, Bp1, b1, raw, psumL(1), psqL(1));
  k_bnfinal<<<1, 128, 0, stream>>>(psumL(1), psqL(1), gamma+1*HID, beta+1*HID, scaleL(1), shiftL(1));
  k_transform<<<(N_NODES*16+255)/256, 256, 0, stream>>>(raw, scaleL(1), shiftL(1), F2);

  // ---- layer 2 ----
  k_agg<HID><<<N_NODES/4, 256, 0, stream>>>(F2, eidx, rowptr, invdeg);
  k_gemm<256><<<GEMM_BLKS, 256, 0, stream>>>(F2, Bp2, b2, raw, psumL(2), psqL(2));
  k_bnfinal<<<1, 128, 0, stream>>>(psumL(2), psqL(2), gamma+2*HID, beta+2*HID, scaleL(2), shiftL(2));

  // ---- pool (applies BN2+ReLU) + MLP head ----
  k_pool<<<(N_NODES+31)/32, 128, 0, stream>>>(raw, batch, scaleL(2), shiftL(2), pooled, cnt);
  k_mlp<<<NUM_GRAPHS, 64, 0, stream>>>(pooled, cnt, fc1W, fc1b, fc2W, fc2b, out);
}